// Round 1
// baseline (1840.197 us; speedup 1.0000x reference)
//
#include <hip/hip_runtime.h>
#include <hip/hip_bf16.h>
#include <cstdint>

typedef unsigned short u16;
typedef __attribute__((ext_vector_type(8))) short s16x8;
typedef __attribute__((ext_vector_type(4))) float f32x4;
typedef __attribute__((ext_vector_type(4))) u16 u16x4;

constexpr int Bc = 2, Tc = 4096, Dc = 1024, Lc = 2, Hc = 16, Fc = 4096, Kc = 2048, DHc = 64;
constexpr int Mc = Bc * Kc;   // 4096 gathered rows (both batches stacked)

__device__ __forceinline__ u16 f2b(float f) {
  __hip_bfloat16 h = __float2bfloat16(f);
  return *reinterpret_cast<u16*>(&h);
}

__device__ __forceinline__ float wred_sum(float v) {
#pragma unroll
  for (int m = 32; m >= 1; m >>= 1) v += __shfl_xor(v, m, 64);
  return v;
}

__device__ __forceinline__ void gl2lds16(const void* g, void* l) {
  __builtin_amdgcn_global_load_lds(
      (const __attribute__((address_space(1))) void*)(uintptr_t)g,
      (__attribute__((address_space(3))) void*)(uintptr_t)l, 16, 0, 0);
}

// ---------------- weight transpose f32(R,C) -> bf16(C,R) ----------------
__global__ void transp_kernel(const float* __restrict__ in, u16* __restrict__ out, int R, int C) {
  __shared__ float t[32][33];
  int c0 = blockIdx.x * 32, r0 = blockIdx.y * 32;
  int tr = threadIdx.x >> 5, tc = threadIdx.x & 31;
#pragma unroll
  for (int i = 0; i < 4; i++)
    t[tr + i * 8][tc] = in[(size_t)(r0 + tr + i * 8) * C + c0 + tc];
  __syncthreads();
#pragma unroll
  for (int i = 0; i < 4; i++)
    out[(size_t)(c0 + tr + i * 8) * R + r0 + tc] = f2b(t[tc][tr + i * 8]);
}

// ---------------- router: logits = x . w + b ----------------
__global__ void router_kernel(const float* __restrict__ x, const float* __restrict__ wr,
                              const float* __restrict__ br, float* __restrict__ out_lg,
                              float* __restrict__ ws_lg) {
  int tid = threadIdx.x, w = tid >> 6, l = tid & 63;
  int token = blockIdx.x * 4 + w;
  const float4* xr = (const float4*)(x + (size_t)token * Dc);
  const float4* wv = (const float4*)wr;
  float acc = 0.f;
#pragma unroll
  for (int i = 0; i < 4; i++) {
    float4 a = xr[l + i * 64], bw = wv[l + i * 64];
    acc += a.x * bw.x + a.y * bw.y + a.z * bw.z + a.w * bw.w;
  }
  acc = wred_sum(acc);
  if (l == 0) {
    float v = acc + br[0];
    out_lg[token] = v;
    ws_lg[token] = v;
  }
}

// ---------------- top-K selection (expert-choice), per batch ----------------
__global__ void topk_kernel(const float* __restrict__ logits, int* __restrict__ idxi,
                            float* __restrict__ gate, int* __restrict__ inv,
                            float* __restrict__ out_idx) {
  __shared__ float lg[Tc];
  __shared__ int sel[Tc];
  int b = blockIdx.x, tid = threadIdx.x;
  for (int i = tid; i < Tc; i += 1024) lg[i] = logits[b * Tc + i];
  __syncthreads();
#pragma unroll
  for (int j = 0; j < 4; j++) {
    int t = tid + j * 1024;
    float mv = lg[t];
    int cnt = 0;
    for (int s2 = 0; s2 < Tc; ++s2) {
      float v = lg[s2];
      cnt += (v > mv) || (v == mv && s2 < t);
    }
    sel[t] = (cnt < Kc) ? 1 : 0;
  }
  __syncthreads();
#pragma unroll
  for (int j = 0; j < 4; j++) {
    int t = tid + j * 1024;
    if (sel[t]) {
      int pos = 0;
      for (int s2 = 0; s2 < t; ++s2) pos += sel[s2];
      idxi[b * Kc + pos] = t;
      out_idx[b * Kc + pos] = (float)t;
      gate[b * Kc + pos] = 1.f / (1.f + __expf(-lg[t]));
      inv[b * Tc + t] = pos;
    } else {
      inv[b * Tc + t] = -1;
    }
  }
}

// ---------------- gather h = x[idx] ----------------
__global__ void gather_kernel(const float* __restrict__ x, const int* __restrict__ idxi,
                              float* __restrict__ h) {
  int blk = blockIdx.x, tid = threadIdx.x;
  int b = blk >> 11;
  int t = idxi[blk];
  ((float4*)(h + (size_t)blk * Dc))[tid] =
      ((const float4*)(x + ((size_t)b * Tc + t) * Dc))[tid];
}

// ---------------- LayerNorm f32 -> bf16 ----------------
__global__ void ln_kernel(const float* __restrict__ h, const float* __restrict__ sc,
                          const float* __restrict__ bi, u16* __restrict__ out) {
  __shared__ float red[8];
  int row = blockIdx.x, tid = threadIdx.x, w = tid >> 6, l = tid & 63;
  float4 v = ((const float4*)(h + (size_t)row * Dc))[tid];
  float s = v.x + v.y + v.z + v.w;
  float q = v.x * v.x + v.y * v.y + v.z * v.z + v.w * v.w;
  s = wred_sum(s);
  q = wred_sum(q);
  if (l == 0) { red[w] = s; red[w + 4] = q; }
  __syncthreads();
  s = red[0] + red[1] + red[2] + red[3];
  q = red[4] + red[5] + red[6] + red[7];
  float mean = s * (1.f / Dc);
  float var = q * (1.f / Dc) - mean * mean;
  float rsd = rsqrtf(var + 1e-5f);
  float4 scv = ((const float4*)sc)[tid];
  float4 biv = ((const float4*)bi)[tid];
  u16x4 o;
  o.x = f2b((v.x - mean) * rsd * scv.x + biv.x);
  o.y = f2b((v.y - mean) * rsd * scv.y + biv.y);
  o.z = f2b((v.z - mean) * rsd * scv.z + biv.z);
  o.w = f2b((v.w - mean) * rsd * scv.w + biv.w);
  *(u16x4*)(out + (size_t)row * Dc + tid * 4) = o;
}

// ---------------- GEMM: C(MxN) = A(MxKd) * BT(NxKd)^T + bias, fused epilogues ----
// EPI 0: scatter to Q/K (B,H,K,DH) and V^T (B,H,DH,K) bf16
// EPI 1: f32 residual accumulate into outf
// EPI 2: GELU(tanh approx) -> bf16 outb
template <int EPI>
__global__ void gemm_bt(const u16* __restrict__ A, const u16* __restrict__ BT,
                        const float* __restrict__ bias, int Kd, int N,
                        float* __restrict__ outf, u16* __restrict__ outb,
                        u16* __restrict__ qd, u16* __restrict__ kd, u16* __restrict__ vd) {
  __shared__ __align__(16) u16 lsA[128 * 32];
  __shared__ __align__(16) u16 lsB[128 * 32];
  int tid = threadIdx.x;
  int w = tid >> 6, l = tid & 63;
  int wu = __builtin_amdgcn_readfirstlane(w);
  int wr = w >> 1, wc = w & 1;
  int lr = l & 15, lg = l >> 4;
  int bm = blockIdx.y, bn = blockIdx.x;
  int srow = tid >> 2, scol = (tid & 3) * 8;
  const u16* ga = A + (size_t)(bm * 128 + srow) * Kd + scol;
  const u16* gb = BT + (size_t)(bn * 128 + srow) * Kd + scol;
  u16* la = lsA + wu * 512;   // wave chunk: 1024 bytes
  u16* lb = lsB + wu * 512;
  f32x4 acc[4][4] = {};
  for (int kt = 0; kt < Kd; kt += 32) {
    gl2lds16(ga + kt, la);
    gl2lds16(ga + (size_t)64 * Kd + kt, la + 2048);
    gl2lds16(gb + kt, lb);
    gl2lds16(gb + (size_t)64 * Kd + kt, lb + 2048);
    __syncthreads();
    s16x8 af[4], bf[4];
#pragma unroll
    for (int i = 0; i < 4; i++)
      af[i] = *(const s16x8*)&lsA[(wr * 64 + i * 16 + lr) * 32 + lg * 8];
#pragma unroll
    for (int j = 0; j < 4; j++)
      bf[j] = *(const s16x8*)&lsB[(wc * 64 + j * 16 + lr) * 32 + lg * 8];
#pragma unroll
    for (int i = 0; i < 4; i++)
#pragma unroll
      for (int j = 0; j < 4; j++)
        acc[i][j] = __builtin_amdgcn_mfma_f32_16x16x32_bf16(af[i], bf[j], acc[i][j], 0, 0, 0);
    __syncthreads();
  }
  int row0 = bm * 128 + wr * 64 + lg * 4;
  int col0 = bn * 128 + wc * 64 + lr;
#pragma unroll
  for (int i = 0; i < 4; i++) {
#pragma unroll
    for (int j = 0; j < 4; j++) {
      int col = col0 + j * 16;
      float bcol = bias[col];
#pragma unroll
      for (int r = 0; r < 4; r++) {
        int row = row0 + i * 16 + r;
        float v = acc[i][j][r] + bcol;
        if constexpr (EPI == 0) {
          int sec = col >> 10, n1 = col & 1023, hh = n1 >> 6, dh = n1 & 63;
          int b = row >> 11, kq = row & 2047;
          size_t bh = (size_t)(b * Hc + hh);
          u16 uv = f2b(v);
          if (sec == 0)      qd[(bh * Kc + kq) * DHc + dh] = uv;
          else if (sec == 1) kd[(bh * Kc + kq) * DHc + dh] = uv;
          else               vd[(bh * DHc + dh) * Kc + kq] = uv;
        } else if constexpr (EPI == 1) {
          outf[(size_t)row * N + col] += v;
        } else {
          float z = 0.7978845608028654f * (v + 0.044715f * v * v * v);
          float g = v / (1.f + __expf(-2.f * z));
          outb[(size_t)row * N + col] = f2b(g);
        }
      }
    }
  }
}

// ---------------- flash attention (causal), 4 waves x 16 q-rows ----------------
__global__ void attn_fwd(const u16* __restrict__ Q, const u16* __restrict__ Kb,
                         const u16* __restrict__ Vt, u16* __restrict__ O) {
  __shared__ __align__(16) u16 pl[4][16 * 32];
  int tid = threadIdx.x, w = tid >> 6, l = tid & 63;
  int lr = l & 15, lg = l >> 4;
  int bid = blockIdx.x;
  int qb = bid & 31, bh = bid >> 5;
  const u16* Qp = Q + (size_t)bh * Kc * DHc;
  const u16* Kp = Kb + (size_t)bh * Kc * DHc;
  const u16* Vp = Vt + (size_t)bh * DHc * Kc;
  int q0 = qb * 64 + w * 16;
  s16x8 qf[2];
  qf[0] = *(const s16x8*)(Qp + (size_t)(q0 + lr) * DHc + lg * 8);
  qf[1] = *(const s16x8*)(Qp + (size_t)(q0 + lr) * DHc + 32 + lg * 8);
  f32x4 oa[4] = {};
  float m_i[4], l_i[4];
#pragma unroll
  for (int r = 0; r < 4; r++) { m_i[r] = -INFINITY; l_i[r] = 0.f; }
  u16* pw = pl[w];
  int kv_end = q0 + 16;
  for (int kv0 = 0; kv0 < kv_end; kv0 += 32) {
    f32x4 s[2] = {};
#pragma unroll
    for (int cf = 0; cf < 2; ++cf) {
      const u16* kp = Kp + (size_t)(kv0 + cf * 16 + lr) * DHc + lg * 8;
      s[cf] = __builtin_amdgcn_mfma_f32_16x16x32_bf16(qf[0], *(const s16x8*)kp, s[cf], 0, 0, 0);
      s[cf] = __builtin_amdgcn_mfma_f32_16x16x32_bf16(qf[1], *(const s16x8*)(kp + 32), s[cf], 0, 0, 0);
    }
    float mt[4];
#pragma unroll
    for (int r = 0; r < 4; r++) {
      int qrow = q0 + lg * 4 + r;
      float s0 = s[0][r] * 0.125f;
      if (kv0 + lr > qrow) s0 = -INFINITY;
      float s1 = s[1][r] * 0.125f;
      if (kv0 + 16 + lr > qrow) s1 = -INFINITY;
      s[0][r] = s0; s[1][r] = s1;
      mt[r] = fmaxf(s0, s1);
    }
#pragma unroll
    for (int msk = 1; msk < 16; msk <<= 1)
#pragma unroll
      for (int r = 0; r < 4; r++) mt[r] = fmaxf(mt[r], __shfl_xor(mt[r], msk, 64));
    float rs[4];
#pragma unroll
    for (int r = 0; r < 4; r++) {
      float mnew = fmaxf(m_i[r], mt[r]);
      float al = __expf(m_i[r] - mnew);
      float p0 = __expf(s[0][r] - mnew);
      float p1 = __expf(s[1][r] - mnew);
      pw[(lg * 4 + r) * 32 + lr] = f2b(p0);
      pw[(lg * 4 + r) * 32 + 16 + lr] = f2b(p1);
      rs[r] = p0 + p1;
      m_i[r] = mnew;
      l_i[r] *= al;
#pragma unroll
      for (int nf = 0; nf < 4; nf++) oa[nf][r] *= al;
    }
#pragma unroll
    for (int msk = 1; msk < 16; msk <<= 1)
#pragma unroll
      for (int r = 0; r < 4; r++) rs[r] += __shfl_xor(rs[r], msk, 64);
#pragma unroll
    for (int r = 0; r < 4; r++) l_i[r] += rs[r];
    s16x8 pf = *(const s16x8*)&pw[lr * 32 + lg * 8];
#pragma unroll
    for (int nf = 0; nf < 4; nf++) {
      const u16* vp = Vp + (size_t)(nf * 16 + lr) * Kc + kv0 + lg * 8;
      oa[nf] = __builtin_amdgcn_mfma_f32_16x16x32_bf16(pf, *(const s16x8*)vp, oa[nf], 0, 0, 0);
    }
  }
  int b = bh >> 4, hh = bh & 15;
#pragma unroll
  for (int r = 0; r < 4; r++) {
    float invl = 1.f / l_i[r];
    int qrow = q0 + lg * 4 + r;
    u16* orow = O + ((size_t)(b * Kc + qrow) * Dc) + hh * DHc;
#pragma unroll
    for (int nf = 0; nf < 4; nf++)
      orow[nf * 16 + lr] = f2b(oa[nf][r] * invl);
  }
}

// ---------------- final gated scatter-add ----------------
__global__ void scatter_kernel(const float* __restrict__ x, const float* __restrict__ h,
                               const float* __restrict__ gate, const int* __restrict__ inv,
                               float* __restrict__ out) {
  int row = blockIdx.x, tid = threadIdx.x;
  int b = row >> 12;
  float4 xv = ((const float4*)(x + (size_t)row * Dc))[tid];
  int pos = inv[row];
  if (pos >= 0) {
    float g = gate[b * Kc + pos];
    float4 hv = ((const float4*)(h + (size_t)(b * Kc + pos) * Dc))[tid];
    xv.x += g * hv.x; xv.y += g * hv.y; xv.z += g * hv.z; xv.w += g * hv.w;
  }
  ((float4*)(out + (size_t)row * Dc))[tid] = xv;
}

extern "C" void kernel_launch(void* const* d_in, const int* in_sizes, int n_in,
                              void* d_out, int out_size, void* d_ws, size_t ws_size,
                              hipStream_t stream) {
  const float* x = (const float*)d_in[0];
  const float* w_router = (const float*)d_in[1];
  const float* b_router = (const float*)d_in[2];
  const float* ln1_s = (const float*)d_in[3];
  const float* ln1_b = (const float*)d_in[4];
  const float* w_qkv = (const float*)d_in[5];
  const float* b_qkv = (const float*)d_in[6];
  const float* w_o = (const float*)d_in[7];
  const float* b_o = (const float*)d_in[8];
  const float* ln2_s = (const float*)d_in[9];
  const float* ln2_b = (const float*)d_in[10];
  const float* w1 = (const float*)d_in[11];
  const float* b1 = (const float*)d_in[12];
  const float* w2 = (const float*)d_in[13];
  const float* b2 = (const float*)d_in[14];

  float* out_total = (float*)d_out;
  float* out_idx = out_total + (size_t)Bc * Tc * Dc;
  float* out_lg = out_idx + Bc * Kc;

  char* p = (char*)d_ws;
  auto carve = [&](size_t bytes) {
    char* r = p;
    p += (bytes + 255) & ~(size_t)255;
    return r;
  };
  float* lg_ws = (float*)carve((size_t)Bc * Tc * 4);
  int* idx_ws = (int*)carve((size_t)Bc * Kc * 4);
  float* gate_ws = (float*)carve((size_t)Bc * Kc * 4);
  int* inv_ws = (int*)carve((size_t)Bc * Tc * 4);
  float* h_ws = (float*)carve((size_t)Mc * Dc * 4);
  u16* a_bf = (u16*)carve((size_t)Mc * Dc * 2);
  u16* o_bf = (u16*)carve((size_t)Mc * Dc * 2);
  u16* g_bf = (u16*)carve((size_t)Mc * Fc * 2);
  u16* qbuf = (u16*)carve((size_t)Bc * Hc * Kc * DHc * 2);
  u16* kbuf = (u16*)carve((size_t)Bc * Hc * Kc * DHc * 2);
  u16* vtbuf = (u16*)carve((size_t)Bc * Hc * Kc * DHc * 2);
  u16* wqkvT = (u16*)carve((size_t)Lc * 3 * Dc * Dc * 2);
  u16* woT = (u16*)carve((size_t)Lc * Dc * Dc * 2);
  u16* w1T = (u16*)carve((size_t)Lc * Dc * Fc * 2);
  u16* w2T = (u16*)carve((size_t)Lc * Fc * Dc * 2);

  for (int l2 = 0; l2 < Lc; ++l2) {
    transp_kernel<<<dim3(3 * Dc / 32, Dc / 32), 256, 0, stream>>>(
        w_qkv + (size_t)l2 * Dc * 3 * Dc, wqkvT + (size_t)l2 * 3 * Dc * Dc, Dc, 3 * Dc);
    transp_kernel<<<dim3(Dc / 32, Dc / 32), 256, 0, stream>>>(
        w_o + (size_t)l2 * Dc * Dc, woT + (size_t)l2 * Dc * Dc, Dc, Dc);
    transp_kernel<<<dim3(Fc / 32, Dc / 32), 256, 0, stream>>>(
        w1 + (size_t)l2 * Dc * Fc, w1T + (size_t)l2 * Fc * Dc, Dc, Fc);
    transp_kernel<<<dim3(Dc / 32, Fc / 32), 256, 0, stream>>>(
        w2 + (size_t)l2 * Fc * Dc, w2T + (size_t)l2 * Dc * Fc, Fc, Dc);
  }
  router_kernel<<<Bc * Tc / 4, 256, 0, stream>>>(x, w_router, b_router, out_lg, lg_ws);
  topk_kernel<<<Bc, 1024, 0, stream>>>(lg_ws, idx_ws, gate_ws, inv_ws, out_idx);
  gather_kernel<<<Mc, 256, 0, stream>>>(x, idx_ws, h_ws);
  for (int l2 = 0; l2 < Lc; ++l2) {
    ln_kernel<<<Mc, 256, 0, stream>>>(h_ws, ln1_s + l2 * Dc, ln1_b + l2 * Dc, a_bf);
    gemm_bt<0><<<dim3(3 * Dc / 128, Mc / 128), 256, 0, stream>>>(
        a_bf, wqkvT + (size_t)l2 * 3 * Dc * Dc, b_qkv + l2 * 3 * Dc, Dc, 3 * Dc,
        nullptr, nullptr, qbuf, kbuf, vtbuf);
    attn_fwd<<<Bc * Hc * (Kc / 64), 256, 0, stream>>>(qbuf, kbuf, vtbuf, o_bf);
    gemm_bt<1><<<dim3(Dc / 128, Mc / 128), 256, 0, stream>>>(
        o_bf, woT + (size_t)l2 * Dc * Dc, b_o + l2 * Dc, Dc, Dc,
        h_ws, nullptr, nullptr, nullptr, nullptr);
    ln_kernel<<<Mc, 256, 0, stream>>>(h_ws, ln2_s + l2 * Dc, ln2_b + l2 * Dc, a_bf);
    gemm_bt<2><<<dim3(Fc / 128, Mc / 128), 256, 0, stream>>>(
        a_bf, w1T + (size_t)l2 * Fc * Dc, b1 + l2 * Fc, Dc, Fc,
        nullptr, g_bf, nullptr, nullptr, nullptr);
    gemm_bt<1><<<dim3(Dc / 128, Mc / 128), 256, 0, stream>>>(
        g_bf, w2T + (size_t)l2 * Dc * Fc, b2 + l2 * Dc, Fc, Dc,
        h_ws, nullptr, nullptr, nullptr, nullptr);
  }
  scatter_kernel<<<Bc * Tc, 256, 0, stream>>>(x, h_ws, gate_ws, inv_ws, out_total);
}

// Round 2
// 1115.616 us; speedup vs baseline: 1.6495x; 1.6495x over previous
//
#include <hip/hip_runtime.h>
#include <hip/hip_bf16.h>
#include <cstdint>

typedef unsigned short u16;
typedef __attribute__((ext_vector_type(8))) short s16x8;
typedef __attribute__((ext_vector_type(4))) float f32x4;
typedef __attribute__((ext_vector_type(4))) u16 u16x4;

constexpr int Bc = 2, Tc = 4096, Dc = 1024, Lc = 2, Hc = 16, Fc = 4096, Kc = 2048, DHc = 64;
constexpr int Mc = Bc * Kc;   // 4096 gathered rows (both batches stacked)

__device__ __forceinline__ u16 f2b(float f) {
  __hip_bfloat16 h = __float2bfloat16(f);
  return *reinterpret_cast<u16*>(&h);
}

__device__ __forceinline__ float wred_sum(float v) {
#pragma unroll
  for (int m = 32; m >= 1; m >>= 1) v += __shfl_xor(v, m, 64);
  return v;
}

__device__ __forceinline__ void gl2lds16(const void* g, void* l) {
  __builtin_amdgcn_global_load_lds(
      (const __attribute__((address_space(1))) void*)(uintptr_t)g,
      (__attribute__((address_space(3))) void*)(uintptr_t)l, 16, 0, 0);
}

// ---------------- weight transpose f32(R,C) -> bf16(C,R) ----------------
__global__ void transp_kernel(const float* __restrict__ in, u16* __restrict__ out, int R, int C) {
  __shared__ float t[32][33];
  int c0 = blockIdx.x * 32, r0 = blockIdx.y * 32;
  int tr = threadIdx.x >> 5, tc = threadIdx.x & 31;
#pragma unroll
  for (int i = 0; i < 4; i++)
    t[tr + i * 8][tc] = in[(size_t)(r0 + tr + i * 8) * C + c0 + tc];
  __syncthreads();
#pragma unroll
  for (int i = 0; i < 4; i++)
    out[(size_t)(c0 + tr + i * 8) * R + r0 + tc] = f2b(t[tc][tr + i * 8]);
}

// ---------------- router: logits = x . w + b ----------------
__global__ void router_kernel(const float* __restrict__ x, const float* __restrict__ wr,
                              const float* __restrict__ br, float* __restrict__ out_lg,
                              float* __restrict__ ws_lg) {
  int tid = threadIdx.x, w = tid >> 6, l = tid & 63;
  int token = blockIdx.x * 4 + w;
  const float4* xr = (const float4*)(x + (size_t)token * Dc);
  const float4* wv = (const float4*)wr;
  float acc = 0.f;
#pragma unroll
  for (int i = 0; i < 4; i++) {
    float4 a = xr[l + i * 64], bw = wv[l + i * 64];
    acc += a.x * bw.x + a.y * bw.y + a.z * bw.z + a.w * bw.w;
  }
  acc = wred_sum(acc);
  if (l == 0) {
    float v = acc + br[0];
    out_lg[token] = v;
    ws_lg[token] = v;
  }
}

// ---------------- top-K selection: radix-select + block scan ----------------
// One block of 1024 threads per batch. Key transform makes u32 compare
// equivalent to f32 compare; tie-break = lower index first (matches lax.top_k).
__global__ void topk_kernel(const float* __restrict__ logits, int* __restrict__ idxi,
                            float* __restrict__ gate, int* __restrict__ inv,
                            float* __restrict__ out_idx) {
  __shared__ float lg[Tc];
  __shared__ unsigned int key[Tc];
  __shared__ unsigned int hist[256];
  __shared__ unsigned int sscan[256];
  __shared__ unsigned int wsum[16], woff[16];
  __shared__ unsigned int sel_info[2];  // {prefix, remaining}
  int b = blockIdx.x, tid = threadIdx.x;
#pragma unroll
  for (int j = 0; j < 4; j++) {
    int t = tid + j * 1024;
    float v = logits[b * Tc + t];
    lg[t] = v;
    unsigned int u = __float_as_uint(v);
    key[t] = (u & 0x80000000u) ? ~u : (u | 0x80000000u);
  }
  if (tid == 0) { sel_info[0] = 0u; sel_info[1] = (unsigned int)Kc; }
  __syncthreads();
  // 4-pass radix select (8 bits/pass) for the Kc-th largest key
  for (int pass = 0; pass < 4; ++pass) {
    int shift = 24 - 8 * pass;
    if (tid < 256) hist[tid] = 0u;
    __syncthreads();
    unsigned int prefix = sel_info[0];
#pragma unroll
    for (int j = 0; j < 4; j++) {
      unsigned int k = key[tid + j * 1024];
      if ((unsigned int)(((unsigned long long)k) >> (shift + 8)) == prefix)
        atomicAdd(&hist[(k >> shift) & 255u], 1u);
    }
    __syncthreads();
    if (tid < 256) sscan[tid] = hist[tid];
    __syncthreads();
    for (int s = 1; s < 256; s <<= 1) {
      unsigned int add = 0u;
      if (tid < 256 && tid + s < 256) add = sscan[tid + s];
      __syncthreads();
      if (tid < 256) sscan[tid] += add;
      __syncthreads();
    }
    if (tid < 256) {
      unsigned int above = sscan[tid] - hist[tid];  // count strictly above this bin
      unsigned int rem = sel_info[1];
      if (above < rem && sscan[tid] >= rem) {       // unique bin
        sel_info[0] = (prefix << 8) | (unsigned int)tid;
        sel_info[1] = rem - above;
      }
    }
    __syncthreads();
  }
  unsigned int thr = sel_info[0];
  unsigned int R = sel_info[1];   // # of thr-equal keys to take (by index order)
  // per-thread (4 consecutive elems) counts, packed gt<<16 | eq
  int base = tid * 4;
  unsigned int sgt = 0, seq = 0;
#pragma unroll
  for (int j = 0; j < 4; j++) {
    unsigned int k = key[base + j];
    sgt += (k > thr); seq += (k == thr);
  }
  unsigned int pk = (sgt << 16) | seq;
  int lane = tid & 63, wid = tid >> 6;
  unsigned int inc = pk;
#pragma unroll
  for (int m = 1; m < 64; m <<= 1) {
    unsigned int o = __shfl_up(inc, m, 64);
    if (lane >= m) inc += o;
  }
  if (lane == 63) wsum[wid] = inc;
  __syncthreads();
  if (tid == 0) {
    unsigned int run = 0;
    for (int i2 = 0; i2 < 16; i2++) { woff[i2] = run; run += wsum[i2]; }
  }
  __syncthreads();
  unsigned int exc = inc - pk + woff[wid];
  unsigned int run_gt = exc >> 16, run_eq = exc & 0xFFFFu;
#pragma unroll
  for (int j = 0; j < 4; j++) {
    int t = base + j;
    unsigned int k = key[t];
    bool isgt = k > thr, iseq = (k == thr);
    bool selv = isgt || (iseq && run_eq < R);
    if (selv) {
      unsigned int pos = run_gt + (run_eq < R ? run_eq : R);
      idxi[b * Kc + pos] = t;
      out_idx[b * Kc + pos] = (float)t;
      gate[b * Kc + pos] = 1.f / (1.f + __expf(-lg[t]));
      inv[b * Tc + t] = (int)pos;
    } else {
      inv[b * Tc + t] = -1;
    }
    run_gt += isgt ? 1u : 0u;
    run_eq += iseq ? 1u : 0u;
  }
}

// ---------------- gather h = x[idx] ----------------
__global__ void gather_kernel(const float* __restrict__ x, const int* __restrict__ idxi,
                              float* __restrict__ h) {
  int blk = blockIdx.x, tid = threadIdx.x;
  int b = blk >> 11;
  int t = idxi[blk];
  ((float4*)(h + (size_t)blk * Dc))[tid] =
      ((const float4*)(x + ((size_t)b * Tc + t) * Dc))[tid];
}

// ---------------- LayerNorm f32 -> bf16 ----------------
__global__ void ln_kernel(const float* __restrict__ h, const float* __restrict__ sc,
                          const float* __restrict__ bi, u16* __restrict__ out) {
  __shared__ float red[8];
  int row = blockIdx.x, tid = threadIdx.x, w = tid >> 6, l = tid & 63;
  float4 v = ((const float4*)(h + (size_t)row * Dc))[tid];
  float s = v.x + v.y + v.z + v.w;
  float q = v.x * v.x + v.y * v.y + v.z * v.z + v.w * v.w;
  s = wred_sum(s);
  q = wred_sum(q);
  if (l == 0) { red[w] = s; red[w + 4] = q; }
  __syncthreads();
  s = red[0] + red[1] + red[2] + red[3];
  q = red[4] + red[5] + red[6] + red[7];
  float mean = s * (1.f / Dc);
  float var = q * (1.f / Dc) - mean * mean;
  float rsd = rsqrtf(var + 1e-5f);
  float4 scv = ((const float4*)sc)[tid];
  float4 biv = ((const float4*)bi)[tid];
  u16x4 o;
  o.x = f2b((v.x - mean) * rsd * scv.x + biv.x);
  o.y = f2b((v.y - mean) * rsd * scv.y + biv.y);
  o.z = f2b((v.z - mean) * rsd * scv.z + biv.z);
  o.w = f2b((v.w - mean) * rsd * scv.w + biv.w);
  *(u16x4*)(out + (size_t)row * Dc + tid * 4) = o;
}

// ---------------- GEMM: C(MxN) = A(MxKd) * BT(NxKd)^T + bias, fused epilogues ----
template <int EPI>
__global__ void gemm_bt(const u16* __restrict__ A, const u16* __restrict__ BT,
                        const float* __restrict__ bias, int Kd, int N,
                        float* __restrict__ outf, u16* __restrict__ outb,
                        u16* __restrict__ qd, u16* __restrict__ kd, u16* __restrict__ vd) {
  __shared__ __align__(16) u16 lsA[128 * 32];
  __shared__ __align__(16) u16 lsB[128 * 32];
  int tid = threadIdx.x;
  int w = tid >> 6, l = tid & 63;
  int wu = __builtin_amdgcn_readfirstlane(w);
  int wr = w >> 1, wc = w & 1;
  int lr = l & 15, lg = l >> 4;
  int bm = blockIdx.y, bn = blockIdx.x;
  int srow = tid >> 2, scol = (tid & 3) * 8;
  const u16* ga = A + (size_t)(bm * 128 + srow) * Kd + scol;
  const u16* gb = BT + (size_t)(bn * 128 + srow) * Kd + scol;
  u16* la = lsA + wu * 512;
  u16* lb = lsB + wu * 512;
  f32x4 acc[4][4] = {};
  for (int kt = 0; kt < Kd; kt += 32) {
    gl2lds16(ga + kt, la);
    gl2lds16(ga + (size_t)64 * Kd + kt, la + 2048);
    gl2lds16(gb + kt, lb);
    gl2lds16(gb + (size_t)64 * Kd + kt, lb + 2048);
    __syncthreads();
    s16x8 af[4], bf[4];
#pragma unroll
    for (int i = 0; i < 4; i++)
      af[i] = *(const s16x8*)&lsA[(wr * 64 + i * 16 + lr) * 32 + lg * 8];
#pragma unroll
    for (int j = 0; j < 4; j++)
      bf[j] = *(const s16x8*)&lsB[(wc * 64 + j * 16 + lr) * 32 + lg * 8];
#pragma unroll
    for (int i = 0; i < 4; i++)
#pragma unroll
      for (int j = 0; j < 4; j++)
        acc[i][j] = __builtin_amdgcn_mfma_f32_16x16x32_bf16(af[i], bf[j], acc[i][j], 0, 0, 0);
    __syncthreads();
  }
  int row0 = bm * 128 + wr * 64 + lg * 4;
  int col0 = bn * 128 + wc * 64 + lr;
#pragma unroll
  for (int i = 0; i < 4; i++) {
#pragma unroll
    for (int j = 0; j < 4; j++) {
      int col = col0 + j * 16;
      float bcol = bias[col];
#pragma unroll
      for (int r = 0; r < 4; r++) {
        int row = row0 + i * 16 + r;
        float v = acc[i][j][r] + bcol;
        if constexpr (EPI == 0) {
          int sec = col >> 10, n1 = col & 1023, hh = n1 >> 6, dh = n1 & 63;
          int b = row >> 11, kq = row & 2047;
          size_t bh = (size_t)(b * Hc + hh);
          u16 uv = f2b(v);
          if (sec == 0)      qd[(bh * Kc + kq) * DHc + dh] = uv;
          else if (sec == 1) kd[(bh * Kc + kq) * DHc + dh] = uv;
          else               vd[(bh * DHc + dh) * Kc + kq] = uv;
        } else if constexpr (EPI == 1) {
          outf[(size_t)row * N + col] += v;
        } else {
          float z = 0.7978845608028654f * (v + 0.044715f * v * v * v);
          float g = v / (1.f + __expf(-2.f * z));
          outb[(size_t)row * N + col] = f2b(g);
        }
      }
    }
  }
}

// ---------------- flash attention (causal), 4 waves x 16 q-rows ----------------
__global__ void attn_fwd(const u16* __restrict__ Q, const u16* __restrict__ Kb,
                         const u16* __restrict__ Vt, u16* __restrict__ O) {
  __shared__ __align__(16) u16 pl[4][16 * 32];
  int tid = threadIdx.x, w = tid >> 6, l = tid & 63;
  int lr = l & 15, lg = l >> 4;
  int bid = blockIdx.x;
  int qb = bid & 31, bh = bid >> 5;
  const u16* Qp = Q + (size_t)bh * Kc * DHc;
  const u16* Kp = Kb + (size_t)bh * Kc * DHc;
  const u16* Vp = Vt + (size_t)bh * DHc * Kc;
  int q0 = qb * 64 + w * 16;
  s16x8 qf[2];
  qf[0] = *(const s16x8*)(Qp + (size_t)(q0 + lr) * DHc + lg * 8);
  qf[1] = *(const s16x8*)(Qp + (size_t)(q0 + lr) * DHc + 32 + lg * 8);
  f32x4 oa[4] = {};
  float m_i[4], l_i[4];
#pragma unroll
  for (int r = 0; r < 4; r++) { m_i[r] = -INFINITY; l_i[r] = 0.f; }
  u16* pw = pl[w];
  int kv_end = q0 + 16;
  for (int kv0 = 0; kv0 < kv_end; kv0 += 32) {
    f32x4 s[2] = {};
#pragma unroll
    for (int cf = 0; cf < 2; ++cf) {
      const u16* kp = Kp + (size_t)(kv0 + cf * 16 + lr) * DHc + lg * 8;
      s[cf] = __builtin_amdgcn_mfma_f32_16x16x32_bf16(qf[0], *(const s16x8*)kp, s[cf], 0, 0, 0);
      s[cf] = __builtin_amdgcn_mfma_f32_16x16x32_bf16(qf[1], *(const s16x8*)(kp + 32), s[cf], 0, 0, 0);
    }
    float mt[4];
#pragma unroll
    for (int r = 0; r < 4; r++) {
      int qrow = q0 + lg * 4 + r;
      float s0 = s[0][r] * 0.125f;
      if (kv0 + lr > qrow) s0 = -INFINITY;
      float s1 = s[1][r] * 0.125f;
      if (kv0 + 16 + lr > qrow) s1 = -INFINITY;
      s[0][r] = s0; s[1][r] = s1;
      mt[r] = fmaxf(s0, s1);
    }
#pragma unroll
    for (int msk = 1; msk < 16; msk <<= 1)
#pragma unroll
      for (int r = 0; r < 4; r++) mt[r] = fmaxf(mt[r], __shfl_xor(mt[r], msk, 64));
    float rs[4];
#pragma unroll
    for (int r = 0; r < 4; r++) {
      float mnew = fmaxf(m_i[r], mt[r]);
      float al = __expf(m_i[r] - mnew);
      float p0 = __expf(s[0][r] - mnew);
      float p1 = __expf(s[1][r] - mnew);
      pw[(lg * 4 + r) * 32 + lr] = f2b(p0);
      pw[(lg * 4 + r) * 32 + 16 + lr] = f2b(p1);
      rs[r] = p0 + p1;
      m_i[r] = mnew;
      l_i[r] *= al;
#pragma unroll
      for (int nf = 0; nf < 4; nf++) oa[nf][r] *= al;
    }
#pragma unroll
    for (int msk = 1; msk < 16; msk <<= 1)
#pragma unroll
      for (int r = 0; r < 4; r++) rs[r] += __shfl_xor(rs[r], msk, 64);
#pragma unroll
    for (int r = 0; r < 4; r++) l_i[r] += rs[r];
    s16x8 pf = *(const s16x8*)&pw[lr * 32 + lg * 8];
#pragma unroll
    for (int nf = 0; nf < 4; nf++) {
      const u16* vp = Vp + (size_t)(nf * 16 + lr) * Kc + kv0 + lg * 8;
      oa[nf] = __builtin_amdgcn_mfma_f32_16x16x32_bf16(pf, *(const s16x8*)vp, oa[nf], 0, 0, 0);
    }
  }
  int b = bh >> 4, hh = bh & 15;
#pragma unroll
  for (int r = 0; r < 4; r++) {
    float invl = 1.f / l_i[r];
    int qrow = q0 + lg * 4 + r;
    u16* orow = O + ((size_t)(b * Kc + qrow) * Dc) + hh * DHc;
#pragma unroll
    for (int nf = 0; nf < 4; nf++)
      orow[nf * 16 + lr] = f2b(oa[nf][r] * invl);
  }
}

// ---------------- final gated scatter-add ----------------
__global__ void scatter_kernel(const float* __restrict__ x, const float* __restrict__ h,
                               const float* __restrict__ gate, const int* __restrict__ inv,
                               float* __restrict__ out) {
  int row = blockIdx.x, tid = threadIdx.x;
  int b = row >> 12;
  float4 xv = ((const float4*)(x + (size_t)row * Dc))[tid];
  int pos = inv[row];
  if (pos >= 0) {
    float g = gate[b * Kc + pos];
    float4 hv = ((const float4*)(h + (size_t)(b * Kc + pos) * Dc))[tid];
    xv.x += g * hv.x; xv.y += g * hv.y; xv.z += g * hv.z; xv.w += g * hv.w;
  }
  ((float4*)(out + (size_t)row * Dc))[tid] = xv;
}

extern "C" void kernel_launch(void* const* d_in, const int* in_sizes, int n_in,
                              void* d_out, int out_size, void* d_ws, size_t ws_size,
                              hipStream_t stream) {
  const float* x = (const float*)d_in[0];
  const float* w_router = (const float*)d_in[1];
  const float* b_router = (const float*)d_in[2];
  const float* ln1_s = (const float*)d_in[3];
  const float* ln1_b = (const float*)d_in[4];
  const float* w_qkv = (const float*)d_in[5];
  const float* b_qkv = (const float*)d_in[6];
  const float* w_o = (const float*)d_in[7];
  const float* b_o = (const float*)d_in[8];
  const float* ln2_s = (const float*)d_in[9];
  const float* ln2_b = (const float*)d_in[10];
  const float* w1 = (const float*)d_in[11];
  const float* b1 = (const float*)d_in[12];
  const float* w2 = (const float*)d_in[13];
  const float* b2 = (const float*)d_in[14];

  float* out_total = (float*)d_out;
  float* out_idx = out_total + (size_t)Bc * Tc * Dc;
  float* out_lg = out_idx + Bc * Kc;

  char* p = (char*)d_ws;
  auto carve = [&](size_t bytes) {
    char* r = p;
    p += (bytes + 255) & ~(size_t)255;
    return r;
  };
  float* lg_ws = (float*)carve((size_t)Bc * Tc * 4);
  int* idx_ws = (int*)carve((size_t)Bc * Kc * 4);
  float* gate_ws = (float*)carve((size_t)Bc * Kc * 4);
  int* inv_ws = (int*)carve((size_t)Bc * Tc * 4);
  float* h_ws = (float*)carve((size_t)Mc * Dc * 4);
  u16* a_bf = (u16*)carve((size_t)Mc * Dc * 2);
  u16* o_bf = (u16*)carve((size_t)Mc * Dc * 2);
  u16* g_bf = (u16*)carve((size_t)Mc * Fc * 2);
  u16* qbuf = (u16*)carve((size_t)Bc * Hc * Kc * DHc * 2);
  u16* kbuf = (u16*)carve((size_t)Bc * Hc * Kc * DHc * 2);
  u16* vtbuf = (u16*)carve((size_t)Bc * Hc * Kc * DHc * 2);
  u16* wqkvT = (u16*)carve((size_t)Lc * 3 * Dc * Dc * 2);
  u16* woT = (u16*)carve((size_t)Lc * Dc * Dc * 2);
  u16* w1T = (u16*)carve((size_t)Lc * Dc * Fc * 2);
  u16* w2T = (u16*)carve((size_t)Lc * Fc * Dc * 2);

  for (int l2 = 0; l2 < Lc; ++l2) {
    transp_kernel<<<dim3(3 * Dc / 32, Dc / 32), 256, 0, stream>>>(
        w_qkv + (size_t)l2 * Dc * 3 * Dc, wqkvT + (size_t)l2 * 3 * Dc * Dc, Dc, 3 * Dc);
    transp_kernel<<<dim3(Dc / 32, Dc / 32), 256, 0, stream>>>(
        w_o + (size_t)l2 * Dc * Dc, woT + (size_t)l2 * Dc * Dc, Dc, Dc);
    transp_kernel<<<dim3(Fc / 32, Dc / 32), 256, 0, stream>>>(
        w1 + (size_t)l2 * Dc * Fc, w1T + (size_t)l2 * Fc * Dc, Dc, Fc);
    transp_kernel<<<dim3(Dc / 32, Fc / 32), 256, 0, stream>>>(
        w2 + (size_t)l2 * Fc * Dc, w2T + (size_t)l2 * Dc * Fc, Fc, Dc);
  }
  router_kernel<<<Bc * Tc / 4, 256, 0, stream>>>(x, w_router, b_router, out_lg, lg_ws);
  topk_kernel<<<Bc, 1024, 0, stream>>>(lg_ws, idx_ws, gate_ws, inv_ws, out_idx);
  gather_kernel<<<Mc, 256, 0, stream>>>(x, idx_ws, h_ws);
  for (int l2 = 0; l2 < Lc; ++l2) {
    ln_kernel<<<Mc, 256, 0, stream>>>(h_ws, ln1_s + l2 * Dc, ln1_b + l2 * Dc, a_bf);
    gemm_bt<0><<<dim3(3 * Dc / 128, Mc / 128), 256, 0, stream>>>(
        a_bf, wqkvT + (size_t)l2 * 3 * Dc * Dc, b_qkv + l2 * 3 * Dc, Dc, 3 * Dc,
        nullptr, nullptr, qbuf, kbuf, vtbuf);
    attn_fwd<<<Bc * Hc * (Kc / 64), 256, 0, stream>>>(qbuf, kbuf, vtbuf, o_bf);
    gemm_bt<1><<<dim3(Dc / 128, Mc / 128), 256, 0, stream>>>(
        o_bf, woT + (size_t)l2 * Dc * Dc, b_o + l2 * Dc, Dc, Dc,
        h_ws, nullptr, nullptr, nullptr, nullptr);
    ln_kernel<<<Mc, 256, 0, stream>>>(h_ws, ln2_s + l2 * Dc, ln2_b + l2 * Dc, a_bf);
    gemm_bt<2><<<dim3(Fc / 128, Mc / 128), 256, 0, stream>>>(
        a_bf, w1T + (size_t)l2 * Fc * Dc, b1 + l2 * Fc, Dc, Fc,
        nullptr, g_bf, nullptr, nullptr, nullptr);
    gemm_bt<1><<<dim3(Dc / 128, Mc / 128), 256, 0, stream>>>(
        g_bf, w2T + (size_t)l2 * Dc * Fc, b2 + l2 * Dc, Fc, Dc,
        h_ws, nullptr, nullptr, nullptr, nullptr);
  }
  scatter_kernel<<<Bc * Tc, 256, 0, stream>>>(x, h_ws, gate_ws, inv_ws, out_total);
}

// Round 4
// 765.489 us; speedup vs baseline: 2.4040x; 1.4574x over previous
//
#include <hip/hip_runtime.h>
#include <hip/hip_bf16.h>
#include <cstdint>

typedef unsigned short u16;
typedef __attribute__((ext_vector_type(8))) short s16x8;
typedef __attribute__((ext_vector_type(4))) float f32x4;
typedef __attribute__((ext_vector_type(4))) u16 u16x4;

constexpr int Bc = 2, Tc = 4096, Dc = 1024, Lc = 2, Hc = 16, Fc = 4096, Kc = 2048, DHc = 64;
constexpr int Mc = Bc * Kc;   // 4096 gathered rows (both batches stacked)

__device__ __forceinline__ u16 f2b(float f) {
  __hip_bfloat16 h = __float2bfloat16(f);
  return *reinterpret_cast<u16*>(&h);
}

__device__ __forceinline__ float wred_sum(float v) {
#pragma unroll
  for (int m = 32; m >= 1; m >>= 1) v += __shfl_xor(v, m, 64);
  return v;
}

__device__ __forceinline__ void gl2lds16(const void* g, void* l) {
  __builtin_amdgcn_global_load_lds(
      (const __attribute__((address_space(1))) void*)(uintptr_t)g,
      (__attribute__((address_space(3))) void*)(uintptr_t)l, 16, 0, 0);
}

// ---------------- weight transpose f32(R,C) -> bf16(C,R) ----------------
__global__ void transp_kernel(const float* __restrict__ in, u16* __restrict__ out, int R, int C) {
  __shared__ float t[32][33];
  int c0 = blockIdx.x * 32, r0 = blockIdx.y * 32;
  int tr = threadIdx.x >> 5, tc = threadIdx.x & 31;
#pragma unroll
  for (int i = 0; i < 4; i++)
    t[tr + i * 8][tc] = in[(size_t)(r0 + tr + i * 8) * C + c0 + tc];
  __syncthreads();
#pragma unroll
  for (int i = 0; i < 4; i++)
    out[(size_t)(c0 + tr + i * 8) * R + r0 + tc] = f2b(t[tc][tr + i * 8]);
}

// ---------------- router: logits = x . w + b ----------------
__global__ void router_kernel(const float* __restrict__ x, const float* __restrict__ wr,
                              const float* __restrict__ br, float* __restrict__ out_lg,
                              float* __restrict__ ws_lg) {
  int tid = threadIdx.x, w = tid >> 6, l = tid & 63;
  int token = blockIdx.x * 4 + w;
  const float4* xr = (const float4*)(x + (size_t)token * Dc);
  const float4* wv = (const float4*)wr;
  float acc = 0.f;
#pragma unroll
  for (int i = 0; i < 4; i++) {
    float4 a = xr[l + i * 64], bw = wv[l + i * 64];
    acc += a.x * bw.x + a.y * bw.y + a.z * bw.z + a.w * bw.w;
  }
  acc = wred_sum(acc);
  if (l == 0) {
    float v = acc + br[0];
    out_lg[token] = v;
    ws_lg[token] = v;
  }
}

// ---------------- top-K selection: radix-select + block scan ----------------
__global__ void topk_kernel(const float* __restrict__ logits, int* __restrict__ idxi,
                            float* __restrict__ gate, int* __restrict__ inv,
                            float* __restrict__ out_idx) {
  __shared__ float lg[Tc];
  __shared__ unsigned int key[Tc];
  __shared__ unsigned int hist[256];
  __shared__ unsigned int sscan[256];
  __shared__ unsigned int wsum[16], woff[16];
  __shared__ unsigned int sel_info[2];  // {prefix, remaining}
  int b = blockIdx.x, tid = threadIdx.x;
#pragma unroll
  for (int j = 0; j < 4; j++) {
    int t = tid + j * 1024;
    float v = logits[b * Tc + t];
    lg[t] = v;
    unsigned int u = __float_as_uint(v);
    key[t] = (u & 0x80000000u) ? ~u : (u | 0x80000000u);
  }
  if (tid == 0) { sel_info[0] = 0u; sel_info[1] = (unsigned int)Kc; }
  __syncthreads();
  for (int pass = 0; pass < 4; ++pass) {
    int shift = 24 - 8 * pass;
    if (tid < 256) hist[tid] = 0u;
    __syncthreads();
    unsigned int prefix = sel_info[0];
#pragma unroll
    for (int j = 0; j < 4; j++) {
      unsigned int k = key[tid + j * 1024];
      if ((unsigned int)(((unsigned long long)k) >> (shift + 8)) == prefix)
        atomicAdd(&hist[(k >> shift) & 255u], 1u);
    }
    __syncthreads();
    if (tid < 256) sscan[tid] = hist[tid];
    __syncthreads();
    for (int s = 1; s < 256; s <<= 1) {
      unsigned int add = 0u;
      if (tid < 256 && tid + s < 256) add = sscan[tid + s];
      __syncthreads();
      if (tid < 256) sscan[tid] += add;
      __syncthreads();
    }
    if (tid < 256) {
      unsigned int above = sscan[tid] - hist[tid];
      unsigned int rem = sel_info[1];
      if (above < rem && sscan[tid] >= rem) {
        sel_info[0] = (prefix << 8) | (unsigned int)tid;
        sel_info[1] = rem - above;
      }
    }
    __syncthreads();
  }
  unsigned int thr = sel_info[0];
  unsigned int R = sel_info[1];
  int base = tid * 4;
  unsigned int sgt = 0, seq = 0;
#pragma unroll
  for (int j = 0; j < 4; j++) {
    unsigned int k = key[base + j];
    sgt += (k > thr); seq += (k == thr);
  }
  unsigned int pk = (sgt << 16) | seq;
  int lane = tid & 63, wid = tid >> 6;
  unsigned int inc = pk;
#pragma unroll
  for (int m = 1; m < 64; m <<= 1) {
    unsigned int o = __shfl_up(inc, m, 64);
    if (lane >= m) inc += o;
  }
  if (lane == 63) wsum[wid] = inc;
  __syncthreads();
  if (tid == 0) {
    unsigned int run = 0;
    for (int i2 = 0; i2 < 16; i2++) { woff[i2] = run; run += wsum[i2]; }
  }
  __syncthreads();
  unsigned int exc = inc - pk + woff[wid];
  unsigned int run_gt = exc >> 16, run_eq = exc & 0xFFFFu;
#pragma unroll
  for (int j = 0; j < 4; j++) {
    int t = base + j;
    unsigned int k = key[t];
    bool isgt = k > thr, iseq = (k == thr);
    bool selv = isgt || (iseq && run_eq < R);
    if (selv) {
      unsigned int pos = run_gt + (run_eq < R ? run_eq : R);
      idxi[b * Kc + pos] = t;
      out_idx[b * Kc + pos] = (float)t;
      gate[b * Kc + pos] = 1.f / (1.f + __expf(-lg[t]));
      inv[b * Tc + t] = (int)pos;
    } else {
      inv[b * Tc + t] = -1;
    }
    run_gt += isgt ? 1u : 0u;
    run_eq += iseq ? 1u : 0u;
  }
}

// ---------------- gather h = x[idx] ----------------
__global__ void gather_kernel(const float* __restrict__ x, const int* __restrict__ idxi,
                              float* __restrict__ h) {
  int blk = blockIdx.x, tid = threadIdx.x;
  int b = blk >> 11;
  int t = idxi[blk];
  ((float4*)(h + (size_t)blk * Dc))[tid] =
      ((const float4*)(x + ((size_t)b * Tc + t) * Dc))[tid];
}

// ---------------- LayerNorm f32 -> bf16 ----------------
__global__ void ln_kernel(const float* __restrict__ h, const float* __restrict__ sc,
                          const float* __restrict__ bi, u16* __restrict__ out) {
  __shared__ float red[8];
  int row = blockIdx.x, tid = threadIdx.x, w = tid >> 6, l = tid & 63;
  float4 v = ((const float4*)(h + (size_t)row * Dc))[tid];
  float s = v.x + v.y + v.z + v.w;
  float q = v.x * v.x + v.y * v.y + v.z * v.z + v.w * v.w;
  s = wred_sum(s);
  q = wred_sum(q);
  if (l == 0) { red[w] = s; red[w + 4] = q; }
  __syncthreads();
  s = red[0] + red[1] + red[2] + red[3];
  q = red[4] + red[5] + red[6] + red[7];
  float mean = s * (1.f / Dc);
  float var = q * (1.f / Dc) - mean * mean;
  float rsd = rsqrtf(var + 1e-5f);
  float4 scv = ((const float4*)sc)[tid];
  float4 biv = ((const float4*)bi)[tid];
  u16x4 o;
  o.x = f2b((v.x - mean) * rsd * scv.x + biv.x);
  o.y = f2b((v.y - mean) * rsd * scv.y + biv.y);
  o.z = f2b((v.z - mean) * rsd * scv.z + biv.z);
  o.w = f2b((v.w - mean) * rsd * scv.w + biv.w);
  *(u16x4*)(out + (size_t)row * Dc + tid * 4) = o;
}

// ---------------- GEMM: C(MxN) = A(MxKd) * BT(NxKd)^T + bias, fused epilogues ----
// EPI 0: scatter to Q(pre-scaled by 1/8)/K (B,H,K,DH) and V^T (B,H,DH,K) bf16
// EPI 1: f32 residual accumulate
// EPI 2: GELU -> bf16
template <int EPI>
__global__ void gemm_bt(const u16* __restrict__ A, const u16* __restrict__ BT,
                        const float* __restrict__ bias, int Kd, int N,
                        float* __restrict__ outf, u16* __restrict__ outb,
                        u16* __restrict__ qd, u16* __restrict__ kd, u16* __restrict__ vd) {
  __shared__ __align__(16) u16 lsA[128 * 32];
  __shared__ __align__(16) u16 lsB[128 * 32];
  int tid = threadIdx.x;
  int w = tid >> 6, l = tid & 63;
  int wu = __builtin_amdgcn_readfirstlane(w);
  int wr = w >> 1, wc = w & 1;
  int lr = l & 15, lg = l >> 4;
  int bm = blockIdx.y, bn = blockIdx.x;
  int srow = tid >> 2, scol = (tid & 3) * 8;
  const u16* ga = A + (size_t)(bm * 128 + srow) * Kd + scol;
  const u16* gb = BT + (size_t)(bn * 128 + srow) * Kd + scol;
  u16* la = lsA + wu * 512;
  u16* lb = lsB + wu * 512;
  f32x4 acc[4][4] = {};
  for (int kt = 0; kt < Kd; kt += 32) {
    gl2lds16(ga + kt, la);
    gl2lds16(ga + (size_t)64 * Kd + kt, la + 2048);
    gl2lds16(gb + kt, lb);
    gl2lds16(gb + (size_t)64 * Kd + kt, lb + 2048);
    __syncthreads();
    s16x8 af[4], bf[4];
#pragma unroll
    for (int i = 0; i < 4; i++)
      af[i] = *(const s16x8*)&lsA[(wr * 64 + i * 16 + lr) * 32 + lg * 8];
#pragma unroll
    for (int j = 0; j < 4; j++)
      bf[j] = *(const s16x8*)&lsB[(wc * 64 + j * 16 + lr) * 32 + lg * 8];
#pragma unroll
    for (int i = 0; i < 4; i++)
#pragma unroll
      for (int j = 0; j < 4; j++)
        acc[i][j] = __builtin_amdgcn_mfma_f32_16x16x32_bf16(af[i], bf[j], acc[i][j], 0, 0, 0);
    __syncthreads();
  }
  int row0 = bm * 128 + wr * 64 + lg * 4;
  int col0 = bn * 128 + wc * 64 + lr;
#pragma unroll
  for (int i = 0; i < 4; i++) {
#pragma unroll
    for (int j = 0; j < 4; j++) {
      int col = col0 + j * 16;
      float bcol = bias[col];
#pragma unroll
      for (int r = 0; r < 4; r++) {
        int row = row0 + i * 16 + r;
        float v = acc[i][j][r] + bcol;
        if constexpr (EPI == 0) {
          int sec = col >> 10, n1 = col & 1023, hh = n1 >> 6, dh = n1 & 63;
          int b = row >> 11, kq = row & 2047;
          size_t bh = (size_t)(b * Hc + hh);
          if (sec == 0) {
            qd[(bh * Kc + kq) * DHc + dh] = f2b(v * 0.125f);  // fold 1/sqrt(DH)
          } else if (sec == 1) {
            kd[(bh * Kc + kq) * DHc + dh] = f2b(v);
          } else {
            vd[(bh * DHc + dh) * Kc + kq] = f2b(v);
          }
        } else if constexpr (EPI == 1) {
          outf[(size_t)row * N + col] += v;
        } else {
          float z = 0.7978845608028654f * (v + 0.044715f * v * v * v);
          float g = v / (1.f + __expf(-2.f * z));
          outb[(size_t)row * N + col] = f2b(g);
        }
      }
    }
  }
}

// ---------------- flash attention (causal), fixed-max softmax, LDS-staged KV ----
// Block = 4 waves, q-tile 64 rows (wave w: rows qb*64+w*16 .. +16).
// KV tiles of 64, double-buffered in LDS; heavy blocks (large qb) launch first.
__global__ __launch_bounds__(256) void attn_fwd(const u16* __restrict__ Q,
                                                const u16* __restrict__ Kb,
                                                const u16* __restrict__ Vt,
                                                u16* __restrict__ O) {
  // K tile:  [buf][pd(2)][kv(64)][d(32)]   (64B rows, m97 layout)
  // V^T tile:[buf][ks(2)][dh(64)][kv(32)]
  // P:       per-wave [ks(2)][q(16)][kv(32)]
  __shared__ __align__(16) u16 Kl[2][4096];
  __shared__ __align__(16) u16 Vl[2][4096];
  __shared__ __align__(16) u16 Pl[4][1024];
  int tid = threadIdx.x, w = tid >> 6, l = tid & 63;
  int lr = l & 15, lg = l >> 4;
  int bid = blockIdx.x;
  int qb = 31 - (bid >> 5);          // heavy-first
  int bh = bid & 31;
  const u16* Qp = Q + (size_t)bh * Kc * DHc;
  const u16* Kp = Kb + (size_t)bh * Kc * DHc;
  const u16* Vp = Vt + (size_t)bh * DHc * Kc;
  int q0 = qb * 64 + w * 16;
  s16x8 qf0 = *(const s16x8*)(Qp + (size_t)(q0 + lr) * DHc + lg * 8);
  s16x8 qf1 = *(const s16x8*)(Qp + (size_t)(q0 + lr) * DHc + 32 + lg * 8);
  int skv = tid >> 2;                // staging row 0..63
  int sc8 = (tid & 3) * 8;           // 16B chunk within 64-elem row
  u16* pw = Pl[w];
  f32x4 oa[4] = {};
  float lsum[4] = {0.f, 0.f, 0.f, 0.f};

  auto stage = [&](int buf, int kv0) {
    const u16* kbase = Kp + (size_t)(kv0 + skv) * DHc + sc8;
    gl2lds16(kbase, &Kl[buf][w * 512]);
    gl2lds16(kbase + 32, &Kl[buf][2048 + w * 512]);
    const u16* vbase = Vp + (size_t)skv * Kc + kv0 + sc8;
    gl2lds16(vbase, &Vl[buf][w * 512]);
    gl2lds16(vbase + 32, &Vl[buf][2048 + w * 512]);
  };

  int nsteps = qb + 1;
  stage(0, 0);
  for (int t = 0; t < nsteps; ++t) {
    int cur = t & 1;
    int kv0 = t * 64;
    if (t + 1 < nsteps) {
      stage(cur ^ 1, kv0 + 64);
      asm volatile("s_waitcnt vmcnt(4)" ::: "memory");
    } else {
      asm volatile("s_waitcnt vmcnt(0)" ::: "memory");
    }
    __builtin_amdgcn_s_barrier();
    asm volatile("" ::: "memory");
    // QK^T (Q pre-scaled by 1/8 in the QKV epilogue)
    f32x4 s[4];
#pragma unroll
    for (int f = 0; f < 4; f++) {
      f32x4 z = {};
      z = __builtin_amdgcn_mfma_f32_16x16x32_bf16(
          qf0, *(const s16x8*)&Kl[cur][(f * 16 + lr) * 32 + lg * 8], z, 0, 0, 0);
      s[f] = __builtin_amdgcn_mfma_f32_16x16x32_bf16(
          qf1, *(const s16x8*)&Kl[cur][2048 + (f * 16 + lr) * 32 + lg * 8], z, 0, 0, 0);
    }
    // masked exp (fixed max = 0), lane-local denominator accumulate
#pragma unroll
    for (int f = 0; f < 4; f++) {
      int kv = kv0 + f * 16 + lr;
#pragma unroll
      for (int r = 0; r < 4; r++) {
        int qrow = q0 + lg * 4 + r;
        float p = (kv <= qrow) ? __expf(s[f][r]) : 0.f;
        lsum[r] += p;
        pw[(f >> 1) * 512 + (lg * 4 + r) * 32 + (f & 1) * 16 + lr] = f2b(p);
      }
    }
    // PV
#pragma unroll
    for (int ks = 0; ks < 2; ks++) {
      s16x8 pf = *(const s16x8*)&pw[ks * 512 + lr * 32 + lg * 8];
#pragma unroll
      for (int d4 = 0; d4 < 4; d4++)
        oa[d4] = __builtin_amdgcn_mfma_f32_16x16x32_bf16(
            pf, *(const s16x8*)&Vl[cur][ks * 2048 + (d4 * 16 + lr) * 32 + lg * 8],
            oa[d4], 0, 0, 0);
    }
    asm volatile("" ::: "memory");
    __builtin_amdgcn_s_barrier();
  }
  // reduce denominator across the 16 lanes sharing each q-row
#pragma unroll
  for (int msk = 1; msk < 16; msk <<= 1)
#pragma unroll
    for (int r = 0; r < 4; r++) lsum[r] += __shfl_xor(lsum[r], msk, 64);
  int b = bh >> 4, hh = bh & 15;
#pragma unroll
  for (int r = 0; r < 4; r++) {
    float invl = 1.f / lsum[r];
    int qrow = q0 + lg * 4 + r;
    u16* orow = O + ((size_t)(b * Kc + qrow) * Dc) + hh * DHc;
#pragma unroll
    for (int d4 = 0; d4 < 4; d4++)
      orow[d4 * 16 + lr] = f2b(oa[d4][r] * invl);
  }
}

// ---------------- final gated scatter-add ----------------
__global__ void scatter_kernel(const float* __restrict__ x, const float* __restrict__ h,
                               const float* __restrict__ gate, const int* __restrict__ inv,
                               float* __restrict__ out) {
  int row = blockIdx.x, tid = threadIdx.x;
  int b = row >> 12;
  float4 xv = ((const float4*)(x + (size_t)row * Dc))[tid];
  int pos = inv[row];
  if (pos >= 0) {
    float g = gate[b * Kc + pos];
    float4 hv = ((const float4*)(h + (size_t)(b * Kc + pos) * Dc))[tid];
    xv.x += g * hv.x; xv.y += g * hv.y; xv.z += g * hv.z; xv.w += g * hv.w;
  }
  ((float4*)(out + (size_t)row * Dc))[tid] = xv;
}

extern "C" void kernel_launch(void* const* d_in, const int* in_sizes, int n_in,
                              void* d_out, int out_size, void* d_ws, size_t ws_size,
                              hipStream_t stream) {
  const float* x = (const float*)d_in[0];
  const float* w_router = (const float*)d_in[1];
  const float* b_router = (const float*)d_in[2];
  const float* ln1_s = (const float*)d_in[3];
  const float* ln1_b = (const float*)d_in[4];
  const float* w_qkv = (const float*)d_in[5];
  const float* b_qkv = (const float*)d_in[6];
  const float* w_o = (const float*)d_in[7];
  const float* b_o = (const float*)d_in[8];
  const float* ln2_s = (const float*)d_in[9];
  const float* ln2_b = (const float*)d_in[10];
  const float* w1 = (const float*)d_in[11];
  const float* b1 = (const float*)d_in[12];
  const float* w2 = (const float*)d_in[13];
  const float* b2 = (const float*)d_in[14];

  float* out_total = (float*)d_out;
  float* out_idx = out_total + (size_t)Bc * Tc * Dc;
  float* out_lg = out_idx + Bc * Kc;

  char* p = (char*)d_ws;
  auto carve = [&](size_t bytes) {
    char* r = p;
    p += (bytes + 255) & ~(size_t)255;
    return r;
  };
  float* lg_ws = (float*)carve((size_t)Bc * Tc * 4);
  int* idx_ws = (int*)carve((size_t)Bc * Kc * 4);
  float* gate_ws = (float*)carve((size_t)Bc * Kc * 4);
  int* inv_ws = (int*)carve((size_t)Bc * Tc * 4);
  float* h_ws = (float*)carve((size_t)Mc * Dc * 4);
  u16* a_bf = (u16*)carve((size_t)Mc * Dc * 2);
  u16* o_bf = (u16*)carve((size_t)Mc * Dc * 2);
  u16* g_bf = (u16*)carve((size_t)Mc * Fc * 2);
  u16* qbuf = (u16*)carve((size_t)Bc * Hc * Kc * DHc * 2);
  u16* kbuf = (u16*)carve((size_t)Bc * Hc * Kc * DHc * 2);
  u16* vtbuf = (u16*)carve((size_t)Bc * Hc * Kc * DHc * 2);
  u16* wqkvT = (u16*)carve((size_t)Lc * 3 * Dc * Dc * 2);
  u16* woT = (u16*)carve((size_t)Lc * Dc * Dc * 2);
  u16* w1T = (u16*)carve((size_t)Lc * Dc * Fc * 2);
  u16* w2T = (u16*)carve((size_t)Lc * Fc * Dc * 2);

  for (int l2 = 0; l2 < Lc; ++l2) {
    transp_kernel<<<dim3(3 * Dc / 32, Dc / 32), 256, 0, stream>>>(
        w_qkv + (size_t)l2 * Dc * 3 * Dc, wqkvT + (size_t)l2 * 3 * Dc * Dc, Dc, 3 * Dc);
    transp_kernel<<<dim3(Dc / 32, Dc / 32), 256, 0, stream>>>(
        w_o + (size_t)l2 * Dc * Dc, woT + (size_t)l2 * Dc * Dc, Dc, Dc);
    transp_kernel<<<dim3(Fc / 32, Dc / 32), 256, 0, stream>>>(
        w1 + (size_t)l2 * Dc * Fc, w1T + (size_t)l2 * Fc * Dc, Dc, Fc);
    transp_kernel<<<dim3(Dc / 32, Fc / 32), 256, 0, stream>>>(
        w2 + (size_t)l2 * Fc * Dc, w2T + (size_t)l2 * Dc * Fc, Fc, Dc);
  }
  router_kernel<<<Bc * Tc / 4, 256, 0, stream>>>(x, w_router, b_router, out_lg, lg_ws);
  topk_kernel<<<Bc, 1024, 0, stream>>>(lg_ws, idx_ws, gate_ws, inv_ws, out_idx);
  gather_kernel<<<Mc, 256, 0, stream>>>(x, idx_ws, h_ws);
  for (int l2 = 0; l2 < Lc; ++l2) {
    ln_kernel<<<Mc, 256, 0, stream>>>(h_ws, ln1_s + l2 * Dc, ln1_b + l2 * Dc, a_bf);
    gemm_bt<0><<<dim3(3 * Dc / 128, Mc / 128), 256, 0, stream>>>(
        a_bf, wqkvT + (size_t)l2 * 3 * Dc * Dc, b_qkv + l2 * 3 * Dc, Dc, 3 * Dc,
        nullptr, nullptr, qbuf, kbuf, vtbuf);
    attn_fwd<<<Bc * Hc * (Kc / 64), 256, 0, stream>>>(qbuf, kbuf, vtbuf, o_bf);
    gemm_bt<1><<<dim3(Dc / 128, Mc / 128), 256, 0, stream>>>(
        o_bf, woT + (size_t)l2 * Dc * Dc, b_o + l2 * Dc, Dc, Dc,
        h_ws, nullptr, nullptr, nullptr, nullptr);
    ln_kernel<<<Mc, 256, 0, stream>>>(h_ws, ln2_s + l2 * Dc, ln2_b + l2 * Dc, a_bf);
    gemm_bt<2><<<dim3(Fc / 128, Mc / 128), 256, 0, stream>>>(
        a_bf, w1T + (size_t)l2 * Fc * Dc, b1 + l2 * Fc, Dc, Fc,
        nullptr, g_bf, nullptr, nullptr, nullptr);
    gemm_bt<1><<<dim3(Dc / 128, Mc / 128), 256, 0, stream>>>(
        g_bf, w2T + (size_t)l2 * Dc * Fc, b2 + l2 * Dc, Fc, Dc,
        h_ws, nullptr, nullptr, nullptr, nullptr);
  }
  scatter_kernel<<<Bc * Tc, 256, 0, stream>>>(x, h_ws, gate_ws, inv_ws, out_total);
}

// Round 5
// 746.258 us; speedup vs baseline: 2.4659x; 1.0258x over previous
//
#include <hip/hip_runtime.h>
#include <hip/hip_bf16.h>
#include <cstdint>

typedef unsigned short u16;
typedef __attribute__((ext_vector_type(8))) short s16x8;
typedef __attribute__((ext_vector_type(4))) float f32x4;
typedef __attribute__((ext_vector_type(4))) u16 u16x4;

constexpr int Bc = 2, Tc = 4096, Dc = 1024, Lc = 2, Hc = 16, Fc = 4096, Kc = 2048, DHc = 64;
constexpr int Mc = Bc * Kc;   // 4096 gathered rows (both batches stacked)

__device__ __forceinline__ u16 f2b(float f) {
  __hip_bfloat16 h = __float2bfloat16(f);
  return *reinterpret_cast<u16*>(&h);
}

__device__ __forceinline__ float wred_sum(float v) {
#pragma unroll
  for (int m = 32; m >= 1; m >>= 1) v += __shfl_xor(v, m, 64);
  return v;
}

__device__ __forceinline__ void gl2lds16(const void* g, void* l) {
  __builtin_amdgcn_global_load_lds(
      (const __attribute__((address_space(1))) void*)(uintptr_t)g,
      (__attribute__((address_space(3))) void*)(uintptr_t)l, 16, 0, 0);
}

// ---------------- weight transpose f32(R,C) -> bf16(C,R) ----------------
__global__ void transp_kernel(const float* __restrict__ in, u16* __restrict__ out, int R, int C) {
  __shared__ float t[32][33];
  int c0 = blockIdx.x * 32, r0 = blockIdx.y * 32;
  int tr = threadIdx.x >> 5, tc = threadIdx.x & 31;
#pragma unroll
  for (int i = 0; i < 4; i++)
    t[tr + i * 8][tc] = in[(size_t)(r0 + tr + i * 8) * C + c0 + tc];
  __syncthreads();
#pragma unroll
  for (int i = 0; i < 4; i++)
    out[(size_t)(c0 + tr + i * 8) * R + r0 + tc] = f2b(t[tc][tr + i * 8]);
}

// ---------------- router: logits = x . w + b ----------------
__global__ void router_kernel(const float* __restrict__ x, const float* __restrict__ wr,
                              const float* __restrict__ br, float* __restrict__ out_lg,
                              float* __restrict__ ws_lg) {
  int tid = threadIdx.x, w = tid >> 6, l = tid & 63;
  int token = blockIdx.x * 4 + w;
  const float4* xr = (const float4*)(x + (size_t)token * Dc);
  const float4* wv = (const float4*)wr;
  float acc = 0.f;
#pragma unroll
  for (int i = 0; i < 4; i++) {
    float4 a = xr[l + i * 64], bw = wv[l + i * 64];
    acc += a.x * bw.x + a.y * bw.y + a.z * bw.z + a.w * bw.w;
  }
  acc = wred_sum(acc);
  if (l == 0) {
    float v = acc + br[0];
    out_lg[token] = v;
    ws_lg[token] = v;
  }
}

// ---------------- top-K selection: radix-select + block scan ----------------
__global__ void topk_kernel(const float* __restrict__ logits, int* __restrict__ idxi,
                            float* __restrict__ gate, int* __restrict__ inv,
                            float* __restrict__ out_idx) {
  __shared__ float lg[Tc];
  __shared__ unsigned int key[Tc];
  __shared__ unsigned int hist[256];
  __shared__ unsigned int sscan[256];
  __shared__ unsigned int wsum[16], woff[16];
  __shared__ unsigned int sel_info[2];  // {prefix, remaining}
  int b = blockIdx.x, tid = threadIdx.x;
#pragma unroll
  for (int j = 0; j < 4; j++) {
    int t = tid + j * 1024;
    float v = logits[b * Tc + t];
    lg[t] = v;
    unsigned int u = __float_as_uint(v);
    key[t] = (u & 0x80000000u) ? ~u : (u | 0x80000000u);
  }
  if (tid == 0) { sel_info[0] = 0u; sel_info[1] = (unsigned int)Kc; }
  __syncthreads();
  for (int pass = 0; pass < 4; ++pass) {
    int shift = 24 - 8 * pass;
    if (tid < 256) hist[tid] = 0u;
    __syncthreads();
    unsigned int prefix = sel_info[0];
#pragma unroll
    for (int j = 0; j < 4; j++) {
      unsigned int k = key[tid + j * 1024];
      if ((unsigned int)(((unsigned long long)k) >> (shift + 8)) == prefix)
        atomicAdd(&hist[(k >> shift) & 255u], 1u);
    }
    __syncthreads();
    if (tid < 256) sscan[tid] = hist[tid];
    __syncthreads();
    for (int s = 1; s < 256; s <<= 1) {
      unsigned int add = 0u;
      if (tid < 256 && tid + s < 256) add = sscan[tid + s];
      __syncthreads();
      if (tid < 256) sscan[tid] += add;
      __syncthreads();
    }
    if (tid < 256) {
      unsigned int above = sscan[tid] - hist[tid];
      unsigned int rem = sel_info[1];
      if (above < rem && sscan[tid] >= rem) {
        sel_info[0] = (prefix << 8) | (unsigned int)tid;
        sel_info[1] = rem - above;
      }
    }
    __syncthreads();
  }
  unsigned int thr = sel_info[0];
  unsigned int R = sel_info[1];
  int base = tid * 4;
  unsigned int sgt = 0, seq = 0;
#pragma unroll
  for (int j = 0; j < 4; j++) {
    unsigned int k = key[base + j];
    sgt += (k > thr); seq += (k == thr);
  }
  unsigned int pk = (sgt << 16) | seq;
  int lane = tid & 63, wid = tid >> 6;
  unsigned int inc = pk;
#pragma unroll
  for (int m = 1; m < 64; m <<= 1) {
    unsigned int o = __shfl_up(inc, m, 64);
    if (lane >= m) inc += o;
  }
  if (lane == 63) wsum[wid] = inc;
  __syncthreads();
  if (tid == 0) {
    unsigned int run = 0;
    for (int i2 = 0; i2 < 16; i2++) { woff[i2] = run; run += wsum[i2]; }
  }
  __syncthreads();
  unsigned int exc = inc - pk + woff[wid];
  unsigned int run_gt = exc >> 16, run_eq = exc & 0xFFFFu;
#pragma unroll
  for (int j = 0; j < 4; j++) {
    int t = base + j;
    unsigned int k = key[t];
    bool isgt = k > thr, iseq = (k == thr);
    bool selv = isgt || (iseq && run_eq < R);
    if (selv) {
      unsigned int pos = run_gt + (run_eq < R ? run_eq : R);
      idxi[b * Kc + pos] = t;
      out_idx[b * Kc + pos] = (float)t;
      gate[b * Kc + pos] = 1.f / (1.f + __expf(-lg[t]));
      inv[b * Tc + t] = (int)pos;
    } else {
      inv[b * Tc + t] = -1;
    }
    run_gt += isgt ? 1u : 0u;
    run_eq += iseq ? 1u : 0u;
  }
}

// ---------------- gather h = x[idx] ----------------
__global__ void gather_kernel(const float* __restrict__ x, const int* __restrict__ idxi,
                              float* __restrict__ h) {
  int blk = blockIdx.x, tid = threadIdx.x;
  int b = blk >> 11;
  int t = idxi[blk];
  ((float4*)(h + (size_t)blk * Dc))[tid] =
      ((const float4*)(x + ((size_t)b * Tc + t) * Dc))[tid];
}

// ---------------- LayerNorm f32 -> bf16 ----------------
__global__ void ln_kernel(const float* __restrict__ h, const float* __restrict__ sc,
                          const float* __restrict__ bi, u16* __restrict__ out) {
  __shared__ float red[8];
  int row = blockIdx.x, tid = threadIdx.x, w = tid >> 6, l = tid & 63;
  float4 v = ((const float4*)(h + (size_t)row * Dc))[tid];
  float s = v.x + v.y + v.z + v.w;
  float q = v.x * v.x + v.y * v.y + v.z * v.z + v.w * v.w;
  s = wred_sum(s);
  q = wred_sum(q);
  if (l == 0) { red[w] = s; red[w + 4] = q; }
  __syncthreads();
  s = red[0] + red[1] + red[2] + red[3];
  q = red[4] + red[5] + red[6] + red[7];
  float mean = s * (1.f / Dc);
  float var = q * (1.f / Dc) - mean * mean;
  float rsd = rsqrtf(var + 1e-5f);
  float4 scv = ((const float4*)sc)[tid];
  float4 biv = ((const float4*)bi)[tid];
  u16x4 o;
  o.x = f2b((v.x - mean) * rsd * scv.x + biv.x);
  o.y = f2b((v.y - mean) * rsd * scv.y + biv.y);
  o.z = f2b((v.z - mean) * rsd * scv.z + biv.z);
  o.w = f2b((v.w - mean) * rsd * scv.w + biv.w);
  *(u16x4*)(out + (size_t)row * Dc + tid * 4) = o;
}

// ---------------- GEMM: C(MxN) = A(MxKd) * BT(NxKd)^T + bias ----------------
// Double-buffered LDS (stage-next + counted vmcnt), bijective XCD swizzle,
// optional split-K (blockIdx.z = K-chunk; EPI 1 uses atomicAdd, bias from z==0).
// EPI 0: scatter to Q(pre-scaled 1/8)/K (B,H,K,DH) and V^T (B,H,DH,K) bf16
// EPI 1: f32 residual atomic-accumulate
// EPI 2: GELU -> bf16
template <int EPI>
__global__ __launch_bounds__(256) void gemm_bt(
    const u16* __restrict__ A, const u16* __restrict__ BT,
    const float* __restrict__ bias, int Kd, int kdchunk, int N, int gridN,
    float* __restrict__ outf, u16* __restrict__ outb,
    u16* __restrict__ qd, u16* __restrict__ kd, u16* __restrict__ vd) {
  __shared__ __align__(16) u16 lsA[2][128 * 32];
  __shared__ __align__(16) u16 lsB[2][128 * 32];
  int tid = threadIdx.x;
  int w = tid >> 6, l = tid & 63;
  int wu = __builtin_amdgcn_readfirstlane(w);
  int wr = w >> 1, wc = w & 1;
  int lr = l & 15, lg = l >> 4;
  // bijective XCD swizzle (m204): consecutive same-XCD blocks share an A panel
  int nwg = gridDim.x;
  int orig = blockIdx.x;
  int qq = nwg >> 3, rr = nwg & 7;
  int xcd = orig & 7;
  int wgid = (xcd < rr ? xcd * (qq + 1) : rr * (qq + 1) + (xcd - rr) * qq) + (orig >> 3);
  int bm = wgid / gridN, bn = wgid % gridN;
  int kz = blockIdx.z;
  int k0 = kz * kdchunk;
  int srow = tid >> 2, scol = (tid & 3) * 8;
  const u16* ga = A + (size_t)(bm * 128 + srow) * Kd + k0 + scol;
  const u16* gb = BT + (size_t)(bn * 128 + srow) * Kd + k0 + scol;

  auto stage = [&](int buf, int kt) {
    gl2lds16(ga + kt, &lsA[buf][wu * 512]);
    gl2lds16(ga + (size_t)64 * Kd + kt, &lsA[buf][2048 + wu * 512]);
    gl2lds16(gb + kt, &lsB[buf][wu * 512]);
    gl2lds16(gb + (size_t)64 * Kd + kt, &lsB[buf][2048 + wu * 512]);
  };

  f32x4 acc[4][4] = {};
  int nt = kdchunk >> 5;
  stage(0, 0);
  for (int t = 0; t < nt; ++t) {
    int cur = t & 1;
    if (t + 1 < nt) {
      stage(cur ^ 1, (t + 1) * 32);
      asm volatile("s_waitcnt vmcnt(4)" ::: "memory");
    } else {
      asm volatile("s_waitcnt vmcnt(0)" ::: "memory");
    }
    __builtin_amdgcn_s_barrier();
    asm volatile("" ::: "memory");
    s16x8 af[4], bf[4];
#pragma unroll
    for (int i = 0; i < 4; i++)
      af[i] = *(const s16x8*)&lsA[cur][(wr * 64 + i * 16 + lr) * 32 + lg * 8];
#pragma unroll
    for (int j = 0; j < 4; j++)
      bf[j] = *(const s16x8*)&lsB[cur][(wc * 64 + j * 16 + lr) * 32 + lg * 8];
#pragma unroll
    for (int i = 0; i < 4; i++)
#pragma unroll
      for (int j = 0; j < 4; j++)
        acc[i][j] = __builtin_amdgcn_mfma_f32_16x16x32_bf16(af[i], bf[j], acc[i][j], 0, 0, 0);
    asm volatile("" ::: "memory");
    __builtin_amdgcn_s_barrier();
  }
  int row0 = bm * 128 + wr * 64 + lg * 4;
  int col0 = bn * 128 + wc * 64 + lr;
  bool addb = (kz == 0);
#pragma unroll
  for (int i = 0; i < 4; i++) {
#pragma unroll
    for (int j = 0; j < 4; j++) {
      int col = col0 + j * 16;
      float bcol = addb ? bias[col] : 0.f;
#pragma unroll
      for (int r = 0; r < 4; r++) {
        int row = row0 + i * 16 + r;
        float v = acc[i][j][r] + bcol;
        if constexpr (EPI == 0) {
          int sec = col >> 10, n1 = col & 1023, hh = n1 >> 6, dh = n1 & 63;
          int b = row >> 11, kq = row & 2047;
          size_t bh = (size_t)(b * Hc + hh);
          if (sec == 0) {
            qd[(bh * Kc + kq) * DHc + dh] = f2b(v * 0.125f);  // fold 1/sqrt(DH)
          } else if (sec == 1) {
            kd[(bh * Kc + kq) * DHc + dh] = f2b(v);
          } else {
            vd[(bh * DHc + dh) * Kc + kq] = f2b(v);
          }
        } else if constexpr (EPI == 1) {
          atomicAdd(&outf[(size_t)row * N + col], v);
        } else {
          float z = 0.7978845608028654f * (v + 0.044715f * v * v * v);
          float g = v / (1.f + __expf(-2.f * z));
          outb[(size_t)row * N + col] = f2b(g);
        }
      }
    }
  }
}

// ---------------- flash attention (causal), fixed-max softmax, LDS-staged KV ----
__global__ __launch_bounds__(256) void attn_fwd(const u16* __restrict__ Q,
                                                const u16* __restrict__ Kb,
                                                const u16* __restrict__ Vt,
                                                u16* __restrict__ O) {
  __shared__ __align__(16) u16 Kl[2][4096];
  __shared__ __align__(16) u16 Vl[2][4096];
  __shared__ __align__(16) u16 Pl[4][1024];
  int tid = threadIdx.x, w = tid >> 6, l = tid & 63;
  int lr = l & 15, lg = l >> 4;
  int bid = blockIdx.x;
  int qb = 31 - (bid >> 5);          // heavy-first
  int bh = bid & 31;
  const u16* Qp = Q + (size_t)bh * Kc * DHc;
  const u16* Kp = Kb + (size_t)bh * Kc * DHc;
  const u16* Vp = Vt + (size_t)bh * DHc * Kc;
  int q0 = qb * 64 + w * 16;
  s16x8 qf0 = *(const s16x8*)(Qp + (size_t)(q0 + lr) * DHc + lg * 8);
  s16x8 qf1 = *(const s16x8*)(Qp + (size_t)(q0 + lr) * DHc + 32 + lg * 8);
  int skv = tid >> 2;
  int sc8 = (tid & 3) * 8;
  u16* pw = Pl[w];
  f32x4 oa[4] = {};
  float lsum[4] = {0.f, 0.f, 0.f, 0.f};

  auto stage = [&](int buf, int kv0) {
    const u16* kbase = Kp + (size_t)(kv0 + skv) * DHc + sc8;
    gl2lds16(kbase, &Kl[buf][w * 512]);
    gl2lds16(kbase + 32, &Kl[buf][2048 + w * 512]);
    const u16* vbase = Vp + (size_t)skv * Kc + kv0 + sc8;
    gl2lds16(vbase, &Vl[buf][w * 512]);
    gl2lds16(vbase + 32, &Vl[buf][2048 + w * 512]);
  };

  int nsteps = qb + 1;
  stage(0, 0);
  for (int t = 0; t < nsteps; ++t) {
    int cur = t & 1;
    int kv0 = t * 64;
    if (t + 1 < nsteps) {
      stage(cur ^ 1, kv0 + 64);
      asm volatile("s_waitcnt vmcnt(4)" ::: "memory");
    } else {
      asm volatile("s_waitcnt vmcnt(0)" ::: "memory");
    }
    __builtin_amdgcn_s_barrier();
    asm volatile("" ::: "memory");
    f32x4 s[4];
#pragma unroll
    for (int f = 0; f < 4; f++) {
      f32x4 z = {};
      z = __builtin_amdgcn_mfma_f32_16x16x32_bf16(
          qf0, *(const s16x8*)&Kl[cur][(f * 16 + lr) * 32 + lg * 8], z, 0, 0, 0);
      s[f] = __builtin_amdgcn_mfma_f32_16x16x32_bf16(
          qf1, *(const s16x8*)&Kl[cur][2048 + (f * 16 + lr) * 32 + lg * 8], z, 0, 0, 0);
    }
#pragma unroll
    for (int f = 0; f < 4; f++) {
      int kv = kv0 + f * 16 + lr;
#pragma unroll
      for (int r = 0; r < 4; r++) {
        int qrow = q0 + lg * 4 + r;
        float p = (kv <= qrow) ? __expf(s[f][r]) : 0.f;
        lsum[r] += p;
        pw[(f >> 1) * 512 + (lg * 4 + r) * 32 + (f & 1) * 16 + lr] = f2b(p);
      }
    }
#pragma unroll
    for (int ks = 0; ks < 2; ks++) {
      s16x8 pf = *(const s16x8*)&pw[ks * 512 + lr * 32 + lg * 8];
#pragma unroll
      for (int d4 = 0; d4 < 4; d4++)
        oa[d4] = __builtin_amdgcn_mfma_f32_16x16x32_bf16(
            pf, *(const s16x8*)&Vl[cur][ks * 2048 + (d4 * 16 + lr) * 32 + lg * 8],
            oa[d4], 0, 0, 0);
    }
    asm volatile("" ::: "memory");
    __builtin_amdgcn_s_barrier();
  }
#pragma unroll
  for (int msk = 1; msk < 16; msk <<= 1)
#pragma unroll
    for (int r = 0; r < 4; r++) lsum[r] += __shfl_xor(lsum[r], msk, 64);
  int b = bh >> 4, hh = bh & 15;
#pragma unroll
  for (int r = 0; r < 4; r++) {
    float invl = 1.f / lsum[r];
    int qrow = q0 + lg * 4 + r;
    u16* orow = O + ((size_t)(b * Kc + qrow) * Dc) + hh * DHc;
#pragma unroll
    for (int d4 = 0; d4 < 4; d4++)
      orow[d4 * 16 + lr] = f2b(oa[d4][r] * invl);
  }
}

// ---------------- final gated scatter-add ----------------
__global__ void scatter_kernel(const float* __restrict__ x, const float* __restrict__ h,
                               const float* __restrict__ gate, const int* __restrict__ inv,
                               float* __restrict__ out) {
  int row = blockIdx.x, tid = threadIdx.x;
  int b = row >> 12;
  float4 xv = ((const float4*)(x + (size_t)row * Dc))[tid];
  int pos = inv[row];
  if (pos >= 0) {
    float g = gate[b * Kc + pos];
    float4 hv = ((const float4*)(h + (size_t)(b * Kc + pos) * Dc))[tid];
    xv.x += g * hv.x; xv.y += g * hv.y; xv.z += g * hv.z; xv.w += g * hv.w;
  }
  ((float4*)(out + (size_t)row * Dc))[tid] = xv;
}

extern "C" void kernel_launch(void* const* d_in, const int* in_sizes, int n_in,
                              void* d_out, int out_size, void* d_ws, size_t ws_size,
                              hipStream_t stream) {
  const float* x = (const float*)d_in[0];
  const float* w_router = (const float*)d_in[1];
  const float* b_router = (const float*)d_in[2];
  const float* ln1_s = (const float*)d_in[3];
  const float* ln1_b = (const float*)d_in[4];
  const float* w_qkv = (const float*)d_in[5];
  const float* b_qkv = (const float*)d_in[6];
  const float* w_o = (const float*)d_in[7];
  const float* b_o = (const float*)d_in[8];
  const float* ln2_s = (const float*)d_in[9];
  const float* ln2_b = (const float*)d_in[10];
  const float* w1 = (const float*)d_in[11];
  const float* b1 = (const float*)d_in[12];
  const float* w2 = (const float*)d_in[13];
  const float* b2 = (const float*)d_in[14];

  float* out_total = (float*)d_out;
  float* out_idx = out_total + (size_t)Bc * Tc * Dc;
  float* out_lg = out_idx + Bc * Kc;

  char* p = (char*)d_ws;
  auto carve = [&](size_t bytes) {
    char* r = p;
    p += (bytes + 255) & ~(size_t)255;
    return r;
  };
  float* lg_ws = (float*)carve((size_t)Bc * Tc * 4);
  int* idx_ws = (int*)carve((size_t)Bc * Kc * 4);
  float* gate_ws = (float*)carve((size_t)Bc * Kc * 4);
  int* inv_ws = (int*)carve((size_t)Bc * Tc * 4);
  float* h_ws = (float*)carve((size_t)Mc * Dc * 4);
  u16* a_bf = (u16*)carve((size_t)Mc * Dc * 2);
  u16* o_bf = (u16*)carve((size_t)Mc * Dc * 2);
  u16* g_bf = (u16*)carve((size_t)Mc * Fc * 2);
  u16* qbuf = (u16*)carve((size_t)Bc * Hc * Kc * DHc * 2);
  u16* kbuf = (u16*)carve((size_t)Bc * Hc * Kc * DHc * 2);
  u16* vtbuf = (u16*)carve((size_t)Bc * Hc * Kc * DHc * 2);
  u16* wqkvT = (u16*)carve((size_t)Lc * 3 * Dc * Dc * 2);
  u16* woT = (u16*)carve((size_t)Lc * Dc * Dc * 2);
  u16* w1T = (u16*)carve((size_t)Lc * Dc * Fc * 2);
  u16* w2T = (u16*)carve((size_t)Lc * Fc * Dc * 2);

  for (int l2 = 0; l2 < Lc; ++l2) {
    transp_kernel<<<dim3(3 * Dc / 32, Dc / 32), 256, 0, stream>>>(
        w_qkv + (size_t)l2 * Dc * 3 * Dc, wqkvT + (size_t)l2 * 3 * Dc * Dc, Dc, 3 * Dc);
    transp_kernel<<<dim3(Dc / 32, Dc / 32), 256, 0, stream>>>(
        w_o + (size_t)l2 * Dc * Dc, woT + (size_t)l2 * Dc * Dc, Dc, Dc);
    transp_kernel<<<dim3(Fc / 32, Dc / 32), 256, 0, stream>>>(
        w1 + (size_t)l2 * Dc * Fc, w1T + (size_t)l2 * Fc * Dc, Dc, Fc);
    transp_kernel<<<dim3(Dc / 32, Fc / 32), 256, 0, stream>>>(
        w2 + (size_t)l2 * Fc * Dc, w2T + (size_t)l2 * Dc * Fc, Fc, Dc);
  }
  router_kernel<<<Bc * Tc / 4, 256, 0, stream>>>(x, w_router, b_router, out_lg, lg_ws);
  topk_kernel<<<Bc, 1024, 0, stream>>>(lg_ws, idx_ws, gate_ws, inv_ws, out_idx);
  gather_kernel<<<Mc, 256, 0, stream>>>(x, idx_ws, h_ws);
  for (int l2 = 0; l2 < Lc; ++l2) {
    ln_kernel<<<Mc, 256, 0, stream>>>(h_ws, ln1_s + l2 * Dc, ln1_b + l2 * Dc, a_bf);
    // QKV: M=4096, N=3072, Kd=1024, no split
    gemm_bt<0><<<dim3((3 * Dc / 128) * (Mc / 128), 1, 1), 256, 0, stream>>>(
        a_bf, wqkvT + (size_t)l2 * 3 * Dc * Dc, b_qkv + l2 * 3 * Dc,
        Dc, Dc, 3 * Dc, 3 * Dc / 128, nullptr, nullptr, qbuf, kbuf, vtbuf);
    attn_fwd<<<Bc * Hc * (Kc / 64), 256, 0, stream>>>(qbuf, kbuf, vtbuf, o_bf);
    // W_O: M=4096, N=1024, Kd=1024, split-K 2
    gemm_bt<1><<<dim3((Dc / 128) * (Mc / 128), 1, 2), 256, 0, stream>>>(
        o_bf, woT + (size_t)l2 * Dc * Dc, b_o + l2 * Dc,
        Dc, Dc / 2, Dc, Dc / 128, h_ws, nullptr, nullptr, nullptr, nullptr);
    ln_kernel<<<Mc, 256, 0, stream>>>(h_ws, ln2_s + l2 * Dc, ln2_b + l2 * Dc, a_bf);
    // FFN1: M=4096, N=4096, Kd=1024, no split
    gemm_bt<2><<<dim3((Fc / 128) * (Mc / 128), 1, 1), 256, 0, stream>>>(
        a_bf, w1T + (size_t)l2 * Fc * Dc, b1 + l2 * Fc,
        Dc, Dc, Fc, Fc / 128, nullptr, g_bf, nullptr, nullptr, nullptr);
    // FFN2: M=4096, N=1024, Kd=4096, split-K 4
    gemm_bt<1><<<dim3((Dc / 128) * (Mc / 128), 1, 4), 256, 0, stream>>>(
        g_bf, w2T + (size_t)l2 * Dc * Fc, b2 + l2 * Dc,
        Fc, Fc / 4, Dc, Dc / 128, h_ws, nullptr, nullptr, nullptr, nullptr);
  }
  scatter_kernel<<<Bc * Tc, 256, 0, stream>>>(x, h_ws, gate_ws, inv_ws, out_total);
}